// Round 10
// baseline (413.859 us; speedup 1.0000x reference)
//
#include <hip/hip_runtime.h>
#include <hip/hip_bf16.h>

// EGCL (EGNN layer): N=384 nodes, V=32 vectors, H=128 feats, U=256 width.
// E = N*(N-1) = 147072 fully-connected edges. f32 in/out, bf16 MFMA compute.
// Edges grouped by RECEIVER r: segment sums are in-block reductions.
// R26 (R25 confirmed: prefetch-depth ladder 124->114->111us). Remaining
// stall = the per-block seam: a CU slot can't start block n+1's staging
// until block n fully ends (x4.5 block-rounds). Fix: PERSISTENT blocks.
//  - 512 blocks loop over 4-5 (chunk,r) tiles; next tile's len2 staged
//    into a dedicated Lb[64][40] (5KB) during current tile's gemm2 phase
//    (Lb dead after gemm1; next read is 4 barriers later).
//  - tile-invariant prefetches hoisted OUT of the loop: gemm1 pages p1,
//    all 8 wxl pages pw, bxl bias. p2/p3/p4 stay per-tile (L2-hot).
//  - buffer chain per tile: Lb ->g1-> Ab ->g2-> Bb ->g3-> Ab ->g4-> Bb;
//    phi_x reads Bb, sred aliases Ab. 6 barriers/tile (unchanged).
//  - mi pass back to R22 4-wave form (mired 4KB) -> LDS 77.3KB, 2 blk/CU.
// Node (24-block) + merged repack unchanged from R24/R25.

#define NN 384
#define VV 32
#define HH 128
#define UU 256
#define MM 64            // edges per tile
#define NCHUNK 6         // 6*64 = 384 = 383 edges + 1 pad
#define NTILES (NCHUNK * NN)
#define GRID 512         // persistent blocks (2/CU resident)
#define SS 264           // LDS row stride gemm buffers (256-wide, +8 pad)
#define LS 40            // Lb row stride (32-wide, +8 pad)
#define XS 392           // node xs row stride (384-wide, +8 pad)

typedef __bf16 bf16v8 __attribute__((ext_vector_type(8)));
typedef __bf16 bf16v4 __attribute__((ext_vector_type(4)));
typedef float  f32x4  __attribute__((ext_vector_type(4)));
typedef float  f32x16 __attribute__((ext_vector_type(16)));
typedef unsigned u32x2 __attribute__((ext_vector_type(2)));

__device__ __forceinline__ float fast_rcp(float x) { return __builtin_amdgcn_rcpf(x); }
__device__ __forceinline__ float fast_sqrt(float x) { return __builtin_amdgcn_sqrtf(x); }
__device__ __forceinline__ float fast_silu(float v) {
    return v * __builtin_amdgcn_rcpf(1.f + __expf(-v));
}
__device__ __forceinline__ unsigned pack_silu2(float a, float b) {
    unsigned short l = __builtin_bit_cast(unsigned short, (__bf16)fast_silu(a));
    unsigned short h = __builtin_bit_cast(unsigned short, (__bf16)fast_silu(b));
    return (unsigned)l | ((unsigned)h << 16);
}
__device__ __forceinline__ unsigned pack_bf2(float a, float b) {
    unsigned short l = __builtin_bit_cast(unsigned short, (__bf16)a);
    unsigned short h = __builtin_bit_cast(unsigned short, (__bf16)b);
    return (unsigned)l | ((unsigned)h << 16);
}

// ---------------- repack + cvec/svec ---------------------------------------
// blocks [0,180): fmt32 transpose tiles; [180,340): scalar fmt16;
// [340,724): cvecg+svecg merged (one nf row read, 2 accumulators).
__global__ __launch_bounds__(256)
void repack_all(const float* __restrict__ We1, const float* __restrict__ We2,
                const float* __restrict__ Wx1, const float* __restrict__ Wx2,
                const float* __restrict__ Wh1, const float* __restrict__ Wh2,
                const float* __restrict__ Wxl, const float* __restrict__ Whl,
                const float* __restrict__ nf,
                __bf16* __restrict__ we1p, __bf16* __restrict__ we2p,
                __bf16* __restrict__ wx1p, __bf16* __restrict__ wx2p,
                __bf16* __restrict__ wh1p, __bf16* __restrict__ wh2p,
                __bf16* __restrict__ wxlp, __bf16* __restrict__ whlp,
                float* __restrict__ cvecg, float* __restrict__ svecg) {
    const float s288 = 0.05892556509887896f;   // 1/sqrt(288)
    const float s384 = 0.05103103630798288f;   // 1/sqrt(384)
    const float s16  = 0.0625f;
    const int b   = blockIdx.x;
    const int tid = threadIdx.x;

    if (b < 180) {                               // ---- fmt32 transpose tiles
        __shared__ __bf16 T[32 * 72];
        const float* src; __bf16* dst; int tile; float scale;
        if (b < 4)        { src = We1; dst = we1p; tile = b;       scale = s288; }
        else if (b < 36)  { src = We2; dst = we2p; tile = b - 4;   scale = s16;  }
        else if (b < 68)  { src = Wx1; dst = wx1p; tile = b - 36;  scale = s16;  }
        else if (b < 100) { src = Wx2; dst = wx2p; tile = b - 68;  scale = s16;  }
        else if (b < 148) { src = Wh1; dst = wh1p; tile = b - 100; scale = s384; }
        else              { src = Wh2; dst = wh2p; tile = b - 148; scale = s16;  }
        const int kt0 = tile >> 2, nt0 = tile & 3;
        const int k0 = kt0 * 32, n0 = nt0 * 64;
#pragma unroll
        for (int i = 0; i < 8; ++i) {
            int p = tid + i * 256;
            int k = p >> 6, n = p & 63;
            T[k * 72 + n] = (__bf16)(src[(k0 + k) * 256 + n0 + n] * scale);
        }
        __syncthreads();
        const int ktl = tid >> 7, rem = tid & 127;
        const int n = rem >> 1, kh = rem & 1;
        bf16v8 v;
#pragma unroll
        for (int j = 0; j < 8; ++j)
            v[j] = T[(ktl * 16 + kh * 8 + j) * 72 + n];
        *(bf16v8*)(dst + (kt0 * 2 + ktl) * 4096 + (n0 + n) * 16 + kh * 8) = v;
        return;
    }
    if (b < 340) {      // ---- scalar fmt16: Wxl (8192 el), Whl (32768 el)
        int t = (b - 180) * 256 + tid;
        const float* src; __bf16* dst; int Nout; int idx; float scale;
        if (t < 8192)       { src = Wxl; dst = wxlp; Nout = 32;  idx = t;        scale = 1.0f; }
        else if (t < 40960) { src = Whl; dst = whlp; Nout = 128; idx = t - 8192; scale = s16;  }
        else return;
        int kt  = idx / (Nout * 32);
        int rem = idx - kt * Nout * 32;
        int n   = rem >> 5;
        int kk  = rem & 31;
        dst[idx] = (__bf16)(src[(kt * 32 + kk) * Nout + n] * scale);
        return;
    }
    // ---- merged cvec/svec: node i, two accumulators, nf read once ----
    {
        int i = b - 340;
        float a = 0.f, c = 0.f;
#pragma unroll 4
        for (int k = 0; k < 128; ++k) {
            float nfv = nf[i * HH + k];
            a += nfv * We1[(32 + k) * 256 + tid];
            c += nfv * We1[(160 + k) * 256 + tid];
        }
        svecg[i * UU + tid] = a * s288;
        cvecg[i * UU + tid] = c * s288;
    }
}

// ---- weight prefetch: first NP kt-pages of a gemm's B rows ----------------
template <int NP> struct WPre { bf16v8 w[NP]; };
template <int NP>
__device__ __forceinline__ WPre<NP> prefW(const __bf16* __restrict__ P,
                                          int wave, int lane) {
    const int idx = lane & 31;
    const int kh  = lane >> 5;
    const __bf16* wr = P + (wave * 32 + idx) * 16 + kh * 8;
    WPre<NP> r;
#pragma unroll
    for (int i = 0; i < NP; ++i)
        r.w[i] = *(const bf16v8*)(wr + i * 4096);
    return r;
}

// ---- swapped 64x256 GEMM: yv = packed silu((X @ Wp)^T), in regs -----------
// D: lane holds edge = lane&31 (acc0) / +32 (acc1); cols 8g+4kh+t in-wave.
template <int KT, int NP>
__device__ __forceinline__ void gemmR(const __bf16* X,
                                      const __bf16* __restrict__ P,
                                      int wave, int lane, unsigned* yv,
                                      const WPre<NP>& pre) {
    const int idx = lane & 31;
    const int kh  = lane >> 5;
    f32x16 acc0 = {}, acc1 = {};
    const __bf16* xb = X + idx * SS + kh * 8;
    const __bf16* wr = P + (wave * 32 + idx) * 16 + kh * 8;
#pragma unroll
    for (int kt = 0; kt < KT; ++kt) {
        bf16v8 w  = (kt < NP) ? pre.w[kt < NP ? kt : 0]
                              : *(const bf16v8*)(wr + kt * 4096);
        bf16v8 x0 = *(const bf16v8*)(xb + kt * 16);
        bf16v8 x1 = *(const bf16v8*)(xb + 32 * SS + kt * 16);
        acc0 = __builtin_amdgcn_mfma_f32_32x32x16_bf16(w, x0, acc0, 0, 0, 0);
        acc1 = __builtin_amdgcn_mfma_f32_32x32x16_bf16(w, x1, acc1, 0, 0, 0);
    }
#pragma unroll
    for (int g = 0; g < 4; ++g) {
        yv[2 * g]       = pack_silu2(acc0[4 * g + 0], acc0[4 * g + 1]);
        yv[2 * g + 1]   = pack_silu2(acc0[4 * g + 2], acc0[4 * g + 3]);
        yv[8 + 2 * g]   = pack_silu2(acc1[4 * g + 0], acc1[4 * g + 1]);
        yv[9 + 2 * g]   = pack_silu2(acc1[4 * g + 2], acc1[4 * g + 3]);
    }
}

// writeback: lane's edge row, 4 quads x b64 per acc tile
__device__ __forceinline__ void writeY(__bf16* Y, int wave, int lane,
                                       const unsigned* yv) {
    const int e  = lane & 31;
    const int kh = lane >> 5;
    __bf16* p0 = Y + e * SS + wave * 32 + 4 * kh;
#pragma unroll
    for (int g = 0; g < 4; ++g) {
        u32x2 a = { yv[2 * g], yv[2 * g + 1] };
        u32x2 b = { yv[8 + 2 * g], yv[9 + 2 * g] };
        *(u32x2*)(p0 + g * 8) = a;
        *(u32x2*)(p0 + 32 * SS + g * 8) = b;
    }
}

// ---- gemm1 swapped: yv = silu(len2 @ We1'[0:32] + svec[s] + cvec[r]) ------
// X = Lb (stride LS). Sender is per-lane constant -> svec/cvec f32x4 loads.
__device__ __forceinline__ void gemm1R(const __bf16* X,
                                       int wave, int lane,
                                       const float* __restrict__ cvec,
                                       const float* __restrict__ svecg,
                                       int r, int e0, unsigned* yv,
                                       const WPre<2>& pre) {
    const int idx = lane & 31;
    const int kh  = lane >> 5;
    f32x16 acc0 = {}, acc1 = {};
    const __bf16* xb = X + idx * LS + kh * 8;
    bf16v8 x00 = *(const bf16v8*)(xb);
    bf16v8 x01 = *(const bf16v8*)(xb + 16);
    bf16v8 x10 = *(const bf16v8*)(xb + 32 * LS);
    bf16v8 x11 = *(const bf16v8*)(xb + 32 * LS + 16);
    acc0 = __builtin_amdgcn_mfma_f32_32x32x16_bf16(pre.w[0], x00, acc0, 0, 0, 0);
    acc0 = __builtin_amdgcn_mfma_f32_32x32x16_bf16(pre.w[1], x01, acc0, 0, 0, 0);
    acc1 = __builtin_amdgcn_mfma_f32_32x32x16_bf16(pre.w[0], x10, acc1, 0, 0, 0);
    acc1 = __builtin_amdgcn_mfma_f32_32x32x16_bf16(pre.w[1], x11, acc1, 0, 0, 0);
    int s0 = r + 1 + e0 + idx; if (s0 >= NN) s0 -= NN;
    int s1 = s0 + 32;          if (s1 >= NN) s1 -= NN;
    const int nb = wave * 32 + 4 * kh;
    const float* cp  = cvec + nb;
    const float* sp0 = svecg + s0 * UU + nb;
    const float* sp1 = svecg + s1 * UU + nb;
#pragma unroll
    for (int g = 0; g < 4; ++g) {
        f32x4 c = *(const f32x4*)(cp + 8 * g);
        f32x4 a = *(const f32x4*)(sp0 + 8 * g);
        f32x4 b = *(const f32x4*)(sp1 + 8 * g);
        yv[2 * g]     = pack_silu2(acc0[4 * g + 0] + c[0] + a[0],
                                   acc0[4 * g + 1] + c[1] + a[1]);
        yv[2 * g + 1] = pack_silu2(acc0[4 * g + 2] + c[2] + a[2],
                                   acc0[4 * g + 3] + c[3] + a[3]);
        yv[8 + 2 * g] = pack_silu2(acc1[4 * g + 0] + c[0] + b[0],
                                   acc1[4 * g + 1] + c[1] + b[1]);
        yv[9 + 2 * g] = pack_silu2(acc1[4 * g + 2] + c[2] + b[2],
                                   acc1[4 * g + 3] + c[3] + b[3]);
    }
}

// ---- gemm2 + fused gate partials (silu applied here, packed plain) --------
template <int NP>
__device__ __forceinline__ void gemm2G(const __bf16* X,
                                       const __bf16* __restrict__ P,
                                       int wave, int lane,
                                       const float* __restrict__ winf,
                                       float* __restrict__ gatep, unsigned* yv,
                                       const WPre<NP>& pre) {
    const int idx = lane & 31;
    const int kh  = lane >> 5;
    f32x16 acc0 = {}, acc1 = {};
    const __bf16* xb = X + idx * SS + kh * 8;
    const __bf16* wr = P + (wave * 32 + idx) * 16 + kh * 8;
#pragma unroll
    for (int kt = 0; kt < 16; ++kt) {
        bf16v8 w  = (kt < NP) ? pre.w[kt < NP ? kt : 0]
                              : *(const bf16v8*)(wr + kt * 4096);
        bf16v8 x0 = *(const bf16v8*)(xb + kt * 16);
        bf16v8 x1 = *(const bf16v8*)(xb + 32 * SS + kt * 16);
        acc0 = __builtin_amdgcn_mfma_f32_32x32x16_bf16(w, x0, acc0, 0, 0, 0);
        acc1 = __builtin_amdgcn_mfma_f32_32x32x16_bf16(w, x1, acc1, 0, 0, 0);
    }
    const int nb = wave * 32 + 4 * kh;
    float gp0 = 0.f, gp1 = 0.f;
#pragma unroll
    for (int g = 0; g < 4; ++g) {
        f32x4 wv = *(const f32x4*)(winf + nb + 8 * g);
        float u0 = fast_silu(acc0[4 * g + 0]), u1 = fast_silu(acc0[4 * g + 1]);
        float u2 = fast_silu(acc0[4 * g + 2]), u3 = fast_silu(acc0[4 * g + 3]);
        float v0 = fast_silu(acc1[4 * g + 0]), v1 = fast_silu(acc1[4 * g + 1]);
        float v2 = fast_silu(acc1[4 * g + 2]), v3 = fast_silu(acc1[4 * g + 3]);
        gp0 += u0 * wv[0] + u1 * wv[1] + u2 * wv[2] + u3 * wv[3];
        gp1 += v0 * wv[0] + v1 * wv[1] + v2 * wv[2] + v3 * wv[3];
        yv[2 * g]     = pack_bf2(u0, u1);
        yv[2 * g + 1] = pack_bf2(u2, u3);
        yv[8 + 2 * g] = pack_bf2(v0, v1);
        yv[9 + 2 * g] = pack_bf2(v2, v3);
    }
    gp0 += __shfl_xor(gp0, 32);                 // combine kh col-halves
    gp1 += __shfl_xor(gp1, 32);
    if (kh == 0) {
        gatep[wave * 64 + idx]      = gp0;
        gatep[wave * 64 + 32 + idx] = gp1;
    }
}

// ---- stage: len2 for tile (r, e0) into Lb ---------------------------------
__device__ __forceinline__ void stageLen2(__bf16* __restrict__ Lb,
                                          const float* __restrict__ nv,
                                          int r, int e0, int tid) {
#pragma unroll
    for (int p = tid; p < MM * 16; p += 512) {     // 2 iters, packed b32
        int i = p >> 4, v = (p & 15) << 1;
        int s = r + 1 + e0 + i; if (s >= NN) s -= NN;
        const float* pr = nv + (r * 32 + v) * 3;
        const float* ps = nv + (s * 32 + v) * 3;
        float a0 = pr[0] - ps[0], a1 = pr[1] - ps[1], a2 = pr[2] - ps[2];
        float b0 = pr[3] - ps[3], b1 = pr[4] - ps[4], b2 = pr[5] - ps[5];
        *(unsigned*)&Lb[i * LS + v] = pack_bf2(a0 * a0 + a1 * a1 + a2 * a2,
                                               b0 * b0 + b1 * b1 + b2 * b2);
    }
}

// ------------------ fused edge kernel (persistent blocks) ------------------
__global__ __launch_bounds__(512, 4)
void edge_kernel(const float* __restrict__ nv, const float* __restrict__ nf,
                 const __bf16* __restrict__ we1p, const __bf16* __restrict__ we2p,
                 const __bf16* __restrict__ wx1p, const __bf16* __restrict__ wx2p,
                 const __bf16* __restrict__ wxlp, const float* __restrict__ bxl,
                 const float* __restrict__ winf, const float* __restrict__ cvecg,
                 const float* __restrict__ svecg,
                 float* __restrict__ shift_part, float* __restrict__ mi_part) {
    __shared__ __align__(16) __bf16 Ab[MM * SS];    // 33792 B (sred alias)
    __shared__ __align__(16) __bf16 Bb[MM * SS];    // 33792 B
    __shared__ __align__(16) __bf16 Lb[MM * LS];    // 5120 B (len2 stage)
    __shared__ __align__(16) float mired[4 * 256];  // 4 KB
    __shared__ __align__(16) float gatep[8 * 64];   // 2 KB
    __shared__ float gateb[MM];                     // 256 B   => 77.3 KB

    const int tid  = threadIdx.x;
    const int wave = tid >> 6;
    const int lane = tid & 63;
    const int col  = lane & 15;
    const int q    = lane >> 4;

    // ---- tile-invariant prefetches (live across the whole loop) ----
    WPre<2> p1 = prefW<2>(we1p, wave, lane);
    const int mt = wave >> 1, nt = wave & 1;
    const int v  = nt * 16 + col;
    const float bias = bxl[v];
    bf16v8 pw[8];
#pragma unroll
    for (int kt = 0; kt < 8; ++kt)
        pw[kt] = *(const bf16v8*)(wxlp + kt * 1024 + v * 32 + q * 8);

    // ---- prologue: stage first tile ----
    {
        int t0 = blockIdx.x;
        int c0 = t0 / NN, r0 = t0 - c0 * NN;
        stageLen2(Lb, nv, r0, c0 * MM, tid);
    }
    __syncthreads();                                                   // S0

    for (int t = blockIdx.x; t < NTILES; t += GRID) {
        const int chunk = t / NN;
        const int r     = t - chunk * NN;
        const int e0    = chunk * MM;
        const int tn    = t + GRID;
        const bool hasn = tn < NTILES;

        unsigned yv[16];

        // ---- h1 = silu(len2 @ We1' + svec + cvec): Lb -> Ab ----
        gemm1R(Lb, wave, lane, cvecg + r * UU, svecg, r, e0, yv, p1);
        writeY(Ab, wave, lane, yv);
        WPre<8> p2 = prefW<8>(we2p, wave, lane);
        __syncthreads();                                               // S2

        // ---- m = silu(h1 @ We2') + gate partials: Ab -> Bb ----
        gemm2G(Ab, we2p, wave, lane, winf, gatep, yv, p2);
        writeY(Bb, wave, lane, yv);
        if (hasn) {                       // stage NEXT tile (Lb free now)
            int cn = tn / NN, rn = tn - cn * NN;
            stageLen2(Lb, nv, rn, cn * MM, tid);
        }
        WPre<8> p3 = prefW<8>(wx1p, wave, lane);
        __syncthreads();                                               // S3

        // ---- redundant per-wave gate finalize (all 8 waves) ----
        {
            float s = 0.f;
#pragma unroll
            for (int w = 0; w < 8; ++w)
                s += gatep[w * 64 + lane];
            gateb[lane] = (e0 + lane == NN - 1) ? 0.f   // self-edge pad
                                                : fast_rcp(1.f + __expf(-s * 0.0625f));
        }
        // ---- mi partials: waves 0-3 read m (Bb); overlaps gemm3 ----
        if (tid < 256) {
            const int w   = tid >> 6;
            const int oct = lane & 31;
            const int egh = lane >> 5;
            const int eg  = w * 2 + egh;
            const __bf16* mp = Bb + (eg * 8) * SS + oct * 8;
            f32x4 g0 = *(const f32x4*)(gateb + eg * 8);
            f32x4 g1 = *(const f32x4*)(gateb + eg * 8 + 4);
            float p[8] = {0.f, 0.f, 0.f, 0.f, 0.f, 0.f, 0.f, 0.f};
#pragma unroll
            for (int i = 0; i < 8; ++i) {
                bf16v8 vv = *(const bf16v8*)(mp + i * SS);
                float gv = (i < 4) ? g0[i] : g1[i - 4];
#pragma unroll
                for (int j = 0; j < 8; ++j)
                    p[j] += (float)vv[j] * gv;
            }
#pragma unroll
            for (int j = 0; j < 8; ++j)            // combine eg pair (xor 32)
                p[j] += __shfl_xor(p[j], 32);
            if (egh == 0) {
                f32x4 a = {p[0], p[1], p[2], p[3]};
                f32x4 b = {p[4], p[5], p[6], p[7]};
                *(f32x4*)(mired + w * 256 + oct * 8)     = a;
                *(f32x4*)(mired + w * 256 + oct * 8 + 4) = b;
            }
        }
        // ---- t1 = silu(m @ Wx1'): Bb -> Ab ----
        gemmR<16, 8>(Bb, wx1p, wave, lane, yv, p3);
        writeY(Ab, wave, lane, yv);
        WPre<8> p4 = prefW<8>(wx2p, wave, lane);
        __syncthreads();                                               // S4

        // ---- mi finalize -> plain store; t2 = silu(t1 @ Wx2'): Ab -> Bb --
        if (tid < 256) {
            float s = mired[tid] + mired[256 + tid] + mired[512 + tid] + mired[768 + tid];
            mi_part[(chunk * NN + r) * UU + tid] = s;
        }
        gemmR<16, 8>(Ab, wx2p, wave, lane, yv, p4);
        writeY(Bb, wave, lane, yv);
        __syncthreads();                                               // S5

        // ---- phi_x MFMA + shift; reads Bb; sred -> Ab (dead) ----
        float sp0, sp1, sp2;
        {
            f32x4 acc = {bias, bias, bias, bias};
            const __bf16* xr = Bb + (mt * 16 + col) * SS + q * 8;
#pragma unroll
            for (int kt = 0; kt < 8; ++kt) {
                bf16v8 a = *(const bf16v8*)(xr + kt * 32);
                acc = __builtin_amdgcn_mfma_f32_16x16x32_bf16(a, pw[kt], acc, 0, 0, 0);
            }
            float r0 = nv[(r * 32 + v) * 3 + 0];
            float r1 = nv[(r * 32 + v) * 3 + 1];
            float r2 = nv[(r * 32 + v) * 3 + 2];
            sp0 = 0.f; sp1 = 0.f; sp2 = 0.f;
#pragma unroll
            for (int i = 0; i < 4; ++i) {
                int e = mt * 16 + q * 4 + i;
                int s = r + 1 + e0 + e; if (s >= NN) s -= NN;
                const float* ps = nv + (s * 32 + v) * 3;
                float d0 = r0 - ps[0], d1 = r1 - ps[1], d2 = r2 - ps[2];
                float len = fast_sqrt(fmaxf(d0 * d0 + d1 * d1 + d2 * d2, 1e-20f));
                float w = acc[i] * fast_rcp(1.f + len);   // self-edge -> 0
                sp0 += w * d0; sp1 += w * d1; sp2 += w * d2;
            }
        }
        float* sred = (float*)Ab;                  // [32 v][16 g][3 c] = 6KB
        {
            int g = mt * 4 + q;
            sred[v * 48 + g * 3 + 0] = sp0;
            sred[v * 48 + g * 3 + 1] = sp1;
            sred[v * 48 + g * 3 + 2] = sp2;
        }
        __syncthreads();                                               // S6

        // ---- reduce 16 groups -> plain store shift_part[chunk][r][96] ----
        if (tid < 96) {
            int vv = tid / 3, c = tid - vv * 3;
            float s = 0.f;
#pragma unroll
            for (int g = 0; g < 16; ++g)
                s += sred[vv * 48 + g * 3 + c];
            shift_part[(chunk * NN + r) * 96 + tid] = s;
        }
        __syncthreads();                                               // S1'
    }
}

// ---------------- node MLP (24 blocks x 16 rows, 16x16x32 MFMA) ------------
// B-operand from fmt32-packed weights via page remap:
//   k = q*8+j (q = lane>>4) -> page kt*2 + (q>>1), in-page (q&1)*8.
__global__ __launch_bounds__(512)
void node_kernel(const float* __restrict__ nv, const float* __restrict__ nf,
                 const __bf16* __restrict__ wh1p, const __bf16* __restrict__ wh2p,
                 const __bf16* __restrict__ whlp,
                 const float* __restrict__ shift_part, const float* __restrict__ mi_part,
                 float* __restrict__ out) {
    __shared__ __align__(16) __bf16 xsb[16 * XS];   // [m_i | nf] 16x384
    __shared__ __align__(16) __bf16 h1b[16 * SS];
    __shared__ __align__(16) __bf16 h2b[16 * SS];
    const int tid  = threadIdx.x;
    const int wave = tid >> 6;
    const int lane = tid & 63;
    const int cl   = lane & 15;
    const int q    = lane >> 4;
    const int n0   = blockIdx.x * 16;

    // ---- stage xs = [sum_k mi_part | nf]; vectors_out from shift_part ----
#pragma unroll
    for (int p = tid; p < 16 * 64; p += 512) {      // 2 iters, f32x4 quads
        int i = p >> 6, cq = (p & 63) * 4;
        f32x4 s = {0.f, 0.f, 0.f, 0.f};
#pragma unroll
        for (int k = 0; k < NCHUNK; ++k)
            s += *(const f32x4*)(mi_part + ((k * NN) + n0 + i) * UU + cq);
        bf16v4 bs = { (__bf16)s[0], (__bf16)s[1], (__bf16)s[2], (__bf16)s[3] };
        *(bf16v4*)&xsb[i * XS + cq] = bs;
    }
#pragma unroll
    for (int p = tid; p < 16 * 128; p += 512) {
        int i = p >> 7, c = p & 127;
        xsb[i * XS + 256 + c] = (__bf16)nf[(n0 + i) * HH + c];
    }
#pragma unroll
    for (int p = tid; p < 16 * 96; p += 512) {
        int i = p / 96, j = p - i * 96;
        float s = 0.f;
#pragma unroll
        for (int k = 0; k < NCHUNK; ++k)
            s += shift_part[((k * NN) + n0 + i) * 96 + j];
        out[(n0 + i) * 96 + j] = nv[(n0 + i) * 96 + j] + s * (1.f / 383.f);
    }
    __syncthreads();

    // ---- h1 = silu(xs @ Wh1'): 16 rows, wave covers 32 cols, K=384 ----
    {
        bf16v8 af[12];
        const __bf16* xr = xsb + cl * XS + q * 8;
#pragma unroll
        for (int kt = 0; kt < 12; ++kt)
            af[kt] = *(const bf16v8*)(xr + kt * 32);
#pragma unroll
        for (int nt = 0; nt < 2; ++nt) {
            int n = wave * 32 + nt * 16 + cl;
            f32x4 acc = {0.f, 0.f, 0.f, 0.f};
#pragma unroll
            for (int kt = 0; kt < 12; ++kt) {
                bf16v8 b = *(const bf16v8*)(wh1p + (kt * 2 + (q >> 1)) * 4096
                                            + n * 16 + (q & 1) * 8);
                acc = __builtin_amdgcn_mfma_f32_16x16x32_bf16(af[kt], b, acc, 0, 0, 0);
            }
#pragma unroll
            for (int i = 0; i < 4; ++i)
                h1b[(q * 4 + i) * SS + n] = (__bf16)fast_silu(acc[i]);
        }
    }
    __syncthreads();

    // ---- h2 = silu(h1 @ Wh2'): K=256 ----
    {
        bf16v8 af[8];
        const __bf16* xr = h1b + cl * SS + q * 8;
#pragma unroll
        for (int kt = 0; kt < 8; ++kt)
            af[kt] = *(const bf16v8*)(xr + kt * 32);
#pragma unroll
        for (int nt = 0; nt < 2; ++nt) {
            int n = wave * 32 + nt * 16 + cl;
            f32x4 acc = {0.f, 0.f, 0.f, 0.f};
#pragma unroll
            for (int kt = 0; kt < 8; ++kt) {
                bf16v8 b = *(const bf16v8*)(wh2p + (kt * 2 + (q >> 1)) * 4096
                                            + n * 16 + (q & 1) * 8);
                acc = __builtin_amdgcn_mfma_f32_16x16x32_bf16(af[kt], b, acc, 0, 0, 0);
            }
#pragma unroll
            for (int i = 0; i < 4; ++i)
                h2b[(q * 4 + i) * SS + n] = (__bf16)fast_silu(acc[i]);
        }
    }
    __syncthreads();

    // ---- features_out = h2 @ Whl' + nf  (N=128: 8 waves x 16 cols) ----
    {
        int n = wave * 16 + cl;
        f32x4 acc = {0.f, 0.f, 0.f, 0.f};
        const __bf16* xr = h2b + cl * SS + q * 8;
#pragma unroll
        for (int kt = 0; kt < 8; ++kt) {
            bf16v8 a = *(const bf16v8*)(xr + kt * 32);
            bf16v8 b = *(const bf16v8*)(whlp + kt * 4096 + n * 32 + q * 8);
            acc = __builtin_amdgcn_mfma_f32_16x16x32_bf16(a, b, acc, 0, 0, 0);
        }
#pragma unroll
        for (int i = 0; i < 4; ++i) {
            int row = n0 + q * 4 + i;
            out[NN * 96 + row * HH + n] = acc[i] + nf[row * HH + n];
        }
    }
}

// ------------------------------- launcher ----------------------------------
extern "C" void kernel_launch(void* const* d_in, const int* in_sizes, int n_in,
                              void* d_out, int out_size, void* d_ws, size_t ws_size,
                              hipStream_t stream) {
    const float* nv   = (const float*)d_in[0];
    const float* nf   = (const float*)d_in[1];
    const float* We1  = (const float*)d_in[2];
    const float* We2  = (const float*)d_in[3];
    const float* Wx1  = (const float*)d_in[4];
    const float* Wx2  = (const float*)d_in[5];
    const float* Wxl  = (const float*)d_in[6];
    const float* bxl  = (const float*)d_in[7];
    const float* Winf = (const float*)d_in[8];
    const float* Wh1  = (const float*)d_in[9];
    const float* Wh2  = (const float*)d_in[10];
    const float* Whl  = (const float*)d_in[11];
    float* out = (float*)d_out;

    char* ws = (char*)d_ws;
    float*  mi_part    = (float*)ws;                    // 6*384*256*4 = 2359296
    float*  shift_part = (float*)(ws + 2359296);        // 6*384*96*4  = 884736
    float*  cvecg  = (float*)(ws + 3244032);            // 393216
    float*  svecg  = (float*)(ws + 3637248);            // 393216
    __bf16* we1p   = (__bf16*)(ws + 4030464);           // 16384 (k rows 0..31)
    __bf16* we2p   = (__bf16*)(ws + 4046848);           // 131072
    __bf16* wx1p   = (__bf16*)(ws + 4177920);           // 131072
    __bf16* wx2p   = (__bf16*)(ws + 4308992);           // 131072
    __bf16* wh1p   = (__bf16*)(ws + 4440064);           // 196608
    __bf16* wh2p   = (__bf16*)(ws + 4636672);           // 131072
    __bf16* wxlp   = (__bf16*)(ws + 4767744);           // 16384
    __bf16* whlp   = (__bf16*)(ws + 4784128);           // 65536

    repack_all<<<dim3(724), 256, 0, stream>>>(We1, We2, Wx1, Wx2, Wh1, Wh2, Wxl, Whl,
                                              nf, we1p, we2p, wx1p, wx2p,
                                              wh1p, wh2p, wxlp, whlp, cvecg, svecg);

    edge_kernel<<<dim3(GRID), 512, 0, stream>>>(nv, nf, we1p, we2p, wx1p, wx2p,
                                                wxlp, bxl, Winf, cvecg, svecg,
                                                shift_part, mi_part);
    node_kernel<<<dim3(24), 512, 0, stream>>>(nv, nf, wh1p, wh2p, whlp,
                                              shift_part, mi_part, out);
}

// Round 11
// 406.400 us; speedup vs baseline: 1.0184x; 1.0184x over previous
//
#include <hip/hip_runtime.h>
#include <hip/hip_bf16.h>

// EGCL (EGNN layer): N=384 nodes, V=32 vectors, H=128 feats, U=256 width.
// E = N*(N-1) = 147072 fully-connected edges. f32 in/out, bf16 MFMA compute.
// Edges grouped by RECEIVER r: segment sums are in-block reductions.
// R27 (R26 post-mortem: 321us regression was SCRATCH SPILLS - FETCH 510MB/
// WRITE 225MB = spill traffic from hoisting pw[8]+p1 across the persistent
// loop on top of per-tile WPre<8>. The seam mechanism was never tested.)
// R27 = persistent retry at R25's register profile:
//  - persistent 512 blocks loop over 4-5 tiles; next tile's len2 staged
//    into Lb[64][40] during current tile's gemm2 phase (seam hiding).
//  - pw[8] loads BACK inside the tile body (R25 placement, L2-hot);
//    p2/p3/p4 per-tile WPre<8> exactly as R25. Only p1 (8 VGPR) + bias
//    hoisted. In-loop pressure = R25 + 9 regs -> no spills expected.
// Verification: FETCH ~5MB / WRITE ~3.2MB = spill-free; dur <111 = seam
// confirmed. Node (24-block) + merged repack unchanged.

#define NN 384
#define VV 32
#define HH 128
#define UU 256
#define MM 64            // edges per tile
#define NCHUNK 6         // 6*64 = 384 = 383 edges + 1 pad
#define NTILES (NCHUNK * NN)
#define GRID 512         // persistent blocks (2/CU resident)
#define SS 264           // LDS row stride gemm buffers (256-wide, +8 pad)
#define LS 40            // Lb row stride (32-wide, +8 pad)
#define XS 392           // node xs row stride (384-wide, +8 pad)

typedef __bf16 bf16v8 __attribute__((ext_vector_type(8)));
typedef __bf16 bf16v4 __attribute__((ext_vector_type(4)));
typedef float  f32x4  __attribute__((ext_vector_type(4)));
typedef float  f32x16 __attribute__((ext_vector_type(16)));
typedef unsigned u32x2 __attribute__((ext_vector_type(2)));

__device__ __forceinline__ float fast_rcp(float x) { return __builtin_amdgcn_rcpf(x); }
__device__ __forceinline__ float fast_sqrt(float x) { return __builtin_amdgcn_sqrtf(x); }
__device__ __forceinline__ float fast_silu(float v) {
    return v * __builtin_amdgcn_rcpf(1.f + __expf(-v));
}
__device__ __forceinline__ unsigned pack_silu2(float a, float b) {
    unsigned short l = __builtin_bit_cast(unsigned short, (__bf16)fast_silu(a));
    unsigned short h = __builtin_bit_cast(unsigned short, (__bf16)fast_silu(b));
    return (unsigned)l | ((unsigned)h << 16);
}
__device__ __forceinline__ unsigned pack_bf2(float a, float b) {
    unsigned short l = __builtin_bit_cast(unsigned short, (__bf16)a);
    unsigned short h = __builtin_bit_cast(unsigned short, (__bf16)b);
    return (unsigned)l | ((unsigned)h << 16);
}

// ---------------- repack + cvec/svec ---------------------------------------
// blocks [0,180): fmt32 transpose tiles; [180,340): scalar fmt16;
// [340,724): cvecg+svecg merged (one nf row read, 2 accumulators).
__global__ __launch_bounds__(256)
void repack_all(const float* __restrict__ We1, const float* __restrict__ We2,
                const float* __restrict__ Wx1, const float* __restrict__ Wx2,
                const float* __restrict__ Wh1, const float* __restrict__ Wh2,
                const float* __restrict__ Wxl, const float* __restrict__ Whl,
                const float* __restrict__ nf,
                __bf16* __restrict__ we1p, __bf16* __restrict__ we2p,
                __bf16* __restrict__ wx1p, __bf16* __restrict__ wx2p,
                __bf16* __restrict__ wh1p, __bf16* __restrict__ wh2p,
                __bf16* __restrict__ wxlp, __bf16* __restrict__ whlp,
                float* __restrict__ cvecg, float* __restrict__ svecg) {
    const float s288 = 0.05892556509887896f;   // 1/sqrt(288)
    const float s384 = 0.05103103630798288f;   // 1/sqrt(384)
    const float s16  = 0.0625f;
    const int b   = blockIdx.x;
    const int tid = threadIdx.x;

    if (b < 180) {                               // ---- fmt32 transpose tiles
        __shared__ __bf16 T[32 * 72];
        const float* src; __bf16* dst; int tile; float scale;
        if (b < 4)        { src = We1; dst = we1p; tile = b;       scale = s288; }
        else if (b < 36)  { src = We2; dst = we2p; tile = b - 4;   scale = s16;  }
        else if (b < 68)  { src = Wx1; dst = wx1p; tile = b - 36;  scale = s16;  }
        else if (b < 100) { src = Wx2; dst = wx2p; tile = b - 68;  scale = s16;  }
        else if (b < 148) { src = Wh1; dst = wh1p; tile = b - 100; scale = s384; }
        else              { src = Wh2; dst = wh2p; tile = b - 148; scale = s16;  }
        const int kt0 = tile >> 2, nt0 = tile & 3;
        const int k0 = kt0 * 32, n0 = nt0 * 64;
#pragma unroll
        for (int i = 0; i < 8; ++i) {
            int p = tid + i * 256;
            int k = p >> 6, n = p & 63;
            T[k * 72 + n] = (__bf16)(src[(k0 + k) * 256 + n0 + n] * scale);
        }
        __syncthreads();
        const int ktl = tid >> 7, rem = tid & 127;
        const int n = rem >> 1, kh = rem & 1;
        bf16v8 v;
#pragma unroll
        for (int j = 0; j < 8; ++j)
            v[j] = T[(ktl * 16 + kh * 8 + j) * 72 + n];
        *(bf16v8*)(dst + (kt0 * 2 + ktl) * 4096 + (n0 + n) * 16 + kh * 8) = v;
        return;
    }
    if (b < 340) {      // ---- scalar fmt16: Wxl (8192 el), Whl (32768 el)
        int t = (b - 180) * 256 + tid;
        const float* src; __bf16* dst; int Nout; int idx; float scale;
        if (t < 8192)       { src = Wxl; dst = wxlp; Nout = 32;  idx = t;        scale = 1.0f; }
        else if (t < 40960) { src = Whl; dst = whlp; Nout = 128; idx = t - 8192; scale = s16;  }
        else return;
        int kt  = idx / (Nout * 32);
        int rem = idx - kt * Nout * 32;
        int n   = rem >> 5;
        int kk  = rem & 31;
        dst[idx] = (__bf16)(src[(kt * 32 + kk) * Nout + n] * scale);
        return;
    }
    // ---- merged cvec/svec: node i, two accumulators, nf read once ----
    {
        int i = b - 340;
        float a = 0.f, c = 0.f;
#pragma unroll 4
        for (int k = 0; k < 128; ++k) {
            float nfv = nf[i * HH + k];
            a += nfv * We1[(32 + k) * 256 + tid];
            c += nfv * We1[(160 + k) * 256 + tid];
        }
        svecg[i * UU + tid] = a * s288;
        cvecg[i * UU + tid] = c * s288;
    }
}

// ---- weight prefetch: first NP kt-pages of a gemm's B rows ----------------
template <int NP> struct WPre { bf16v8 w[NP]; };
template <int NP>
__device__ __forceinline__ WPre<NP> prefW(const __bf16* __restrict__ P,
                                          int wave, int lane) {
    const int idx = lane & 31;
    const int kh  = lane >> 5;
    const __bf16* wr = P + (wave * 32 + idx) * 16 + kh * 8;
    WPre<NP> r;
#pragma unroll
    for (int i = 0; i < NP; ++i)
        r.w[i] = *(const bf16v8*)(wr + i * 4096);
    return r;
}

// ---- swapped 64x256 GEMM: yv = packed silu((X @ Wp)^T), in regs -----------
// D: lane holds edge = lane&31 (acc0) / +32 (acc1); cols 8g+4kh+t in-wave.
template <int KT, int NP>
__device__ __forceinline__ void gemmR(const __bf16* X,
                                      const __bf16* __restrict__ P,
                                      int wave, int lane, unsigned* yv,
                                      const WPre<NP>& pre) {
    const int idx = lane & 31;
    const int kh  = lane >> 5;
    f32x16 acc0 = {}, acc1 = {};
    const __bf16* xb = X + idx * SS + kh * 8;
    const __bf16* wr = P + (wave * 32 + idx) * 16 + kh * 8;
#pragma unroll
    for (int kt = 0; kt < KT; ++kt) {
        bf16v8 w  = (kt < NP) ? pre.w[kt < NP ? kt : 0]
                              : *(const bf16v8*)(wr + kt * 4096);
        bf16v8 x0 = *(const bf16v8*)(xb + kt * 16);
        bf16v8 x1 = *(const bf16v8*)(xb + 32 * SS + kt * 16);
        acc0 = __builtin_amdgcn_mfma_f32_32x32x16_bf16(w, x0, acc0, 0, 0, 0);
        acc1 = __builtin_amdgcn_mfma_f32_32x32x16_bf16(w, x1, acc1, 0, 0, 0);
    }
#pragma unroll
    for (int g = 0; g < 4; ++g) {
        yv[2 * g]       = pack_silu2(acc0[4 * g + 0], acc0[4 * g + 1]);
        yv[2 * g + 1]   = pack_silu2(acc0[4 * g + 2], acc0[4 * g + 3]);
        yv[8 + 2 * g]   = pack_silu2(acc1[4 * g + 0], acc1[4 * g + 1]);
        yv[9 + 2 * g]   = pack_silu2(acc1[4 * g + 2], acc1[4 * g + 3]);
    }
}

// writeback: lane's edge row, 4 quads x b64 per acc tile
__device__ __forceinline__ void writeY(__bf16* Y, int wave, int lane,
                                       const unsigned* yv) {
    const int e  = lane & 31;
    const int kh = lane >> 5;
    __bf16* p0 = Y + e * SS + wave * 32 + 4 * kh;
#pragma unroll
    for (int g = 0; g < 4; ++g) {
        u32x2 a = { yv[2 * g], yv[2 * g + 1] };
        u32x2 b = { yv[8 + 2 * g], yv[9 + 2 * g] };
        *(u32x2*)(p0 + g * 8) = a;
        *(u32x2*)(p0 + 32 * SS + g * 8) = b;
    }
}

// ---- gemm1 swapped: yv = silu(len2 @ We1'[0:32] + svec[s] + cvec[r]) ------
// X = Lb (stride LS). Sender is per-lane constant -> svec/cvec f32x4 loads.
__device__ __forceinline__ void gemm1R(const __bf16* X,
                                       int wave, int lane,
                                       const float* __restrict__ cvec,
                                       const float* __restrict__ svecg,
                                       int r, int e0, unsigned* yv,
                                       const WPre<2>& pre) {
    const int idx = lane & 31;
    const int kh  = lane >> 5;
    f32x16 acc0 = {}, acc1 = {};
    const __bf16* xb = X + idx * LS + kh * 8;
    bf16v8 x00 = *(const bf16v8*)(xb);
    bf16v8 x01 = *(const bf16v8*)(xb + 16);
    bf16v8 x10 = *(const bf16v8*)(xb + 32 * LS);
    bf16v8 x11 = *(const bf16v8*)(xb + 32 * LS + 16);
    acc0 = __builtin_amdgcn_mfma_f32_32x32x16_bf16(pre.w[0], x00, acc0, 0, 0, 0);
    acc0 = __builtin_amdgcn_mfma_f32_32x32x16_bf16(pre.w[1], x01, acc0, 0, 0, 0);
    acc1 = __builtin_amdgcn_mfma_f32_32x32x16_bf16(pre.w[0], x10, acc1, 0, 0, 0);
    acc1 = __builtin_amdgcn_mfma_f32_32x32x16_bf16(pre.w[1], x11, acc1, 0, 0, 0);
    int s0 = r + 1 + e0 + idx; if (s0 >= NN) s0 -= NN;
    int s1 = s0 + 32;          if (s1 >= NN) s1 -= NN;
    const int nb = wave * 32 + 4 * kh;
    const float* cp  = cvec + nb;
    const float* sp0 = svecg + s0 * UU + nb;
    const float* sp1 = svecg + s1 * UU + nb;
#pragma unroll
    for (int g = 0; g < 4; ++g) {
        f32x4 c = *(const f32x4*)(cp + 8 * g);
        f32x4 a = *(const f32x4*)(sp0 + 8 * g);
        f32x4 b = *(const f32x4*)(sp1 + 8 * g);
        yv[2 * g]     = pack_silu2(acc0[4 * g + 0] + c[0] + a[0],
                                   acc0[4 * g + 1] + c[1] + a[1]);
        yv[2 * g + 1] = pack_silu2(acc0[4 * g + 2] + c[2] + a[2],
                                   acc0[4 * g + 3] + c[3] + a[3]);
        yv[8 + 2 * g] = pack_silu2(acc1[4 * g + 0] + c[0] + b[0],
                                   acc1[4 * g + 1] + c[1] + b[1]);
        yv[9 + 2 * g] = pack_silu2(acc1[4 * g + 2] + c[2] + b[2],
                                   acc1[4 * g + 3] + c[3] + b[3]);
    }
}

// ---- gemm2 + fused gate partials (silu applied here, packed plain) --------
template <int NP>
__device__ __forceinline__ void gemm2G(const __bf16* X,
                                       const __bf16* __restrict__ P,
                                       int wave, int lane,
                                       const float* __restrict__ winf,
                                       float* __restrict__ gatep, unsigned* yv,
                                       const WPre<NP>& pre) {
    const int idx = lane & 31;
    const int kh  = lane >> 5;
    f32x16 acc0 = {}, acc1 = {};
    const __bf16* xb = X + idx * SS + kh * 8;
    const __bf16* wr = P + (wave * 32 + idx) * 16 + kh * 8;
#pragma unroll
    for (int kt = 0; kt < 16; ++kt) {
        bf16v8 w  = (kt < NP) ? pre.w[kt < NP ? kt : 0]
                              : *(const bf16v8*)(wr + kt * 4096);
        bf16v8 x0 = *(const bf16v8*)(xb + kt * 16);
        bf16v8 x1 = *(const bf16v8*)(xb + 32 * SS + kt * 16);
        acc0 = __builtin_amdgcn_mfma_f32_32x32x16_bf16(w, x0, acc0, 0, 0, 0);
        acc1 = __builtin_amdgcn_mfma_f32_32x32x16_bf16(w, x1, acc1, 0, 0, 0);
    }
    const int nb = wave * 32 + 4 * kh;
    float gp0 = 0.f, gp1 = 0.f;
#pragma unroll
    for (int g = 0; g < 4; ++g) {
        f32x4 wv = *(const f32x4*)(winf + nb + 8 * g);
        float u0 = fast_silu(acc0[4 * g + 0]), u1 = fast_silu(acc0[4 * g + 1]);
        float u2 = fast_silu(acc0[4 * g + 2]), u3 = fast_silu(acc0[4 * g + 3]);
        float v0 = fast_silu(acc1[4 * g + 0]), v1 = fast_silu(acc1[4 * g + 1]);
        float v2 = fast_silu(acc1[4 * g + 2]), v3 = fast_silu(acc1[4 * g + 3]);
        gp0 += u0 * wv[0] + u1 * wv[1] + u2 * wv[2] + u3 * wv[3];
        gp1 += v0 * wv[0] + v1 * wv[1] + v2 * wv[2] + v3 * wv[3];
        yv[2 * g]     = pack_bf2(u0, u1);
        yv[2 * g + 1] = pack_bf2(u2, u3);
        yv[8 + 2 * g] = pack_bf2(v0, v1);
        yv[9 + 2 * g] = pack_bf2(v2, v3);
    }
    gp0 += __shfl_xor(gp0, 32);                 // combine kh col-halves
    gp1 += __shfl_xor(gp1, 32);
    if (kh == 0) {
        gatep[wave * 64 + idx]      = gp0;
        gatep[wave * 64 + 32 + idx] = gp1;
    }
}

// ---- stage: len2 for tile (r, e0) into Lb ---------------------------------
__device__ __forceinline__ void stageLen2(__bf16* __restrict__ Lb,
                                          const float* __restrict__ nv,
                                          int r, int e0, int tid) {
#pragma unroll
    for (int p = tid; p < MM * 16; p += 512) {     // 2 iters, packed b32
        int i = p >> 4, v = (p & 15) << 1;
        int s = r + 1 + e0 + i; if (s >= NN) s -= NN;
        const float* pr = nv + (r * 32 + v) * 3;
        const float* ps = nv + (s * 32 + v) * 3;
        float a0 = pr[0] - ps[0], a1 = pr[1] - ps[1], a2 = pr[2] - ps[2];
        float b0 = pr[3] - ps[3], b1 = pr[4] - ps[4], b2 = pr[5] - ps[5];
        *(unsigned*)&Lb[i * LS + v] = pack_bf2(a0 * a0 + a1 * a1 + a2 * a2,
                                               b0 * b0 + b1 * b1 + b2 * b2);
    }
}

// ------------------ fused edge kernel (persistent blocks) ------------------
__global__ __launch_bounds__(512, 4)
void edge_kernel(const float* __restrict__ nv, const float* __restrict__ nf,
                 const __bf16* __restrict__ we1p, const __bf16* __restrict__ we2p,
                 const __bf16* __restrict__ wx1p, const __bf16* __restrict__ wx2p,
                 const __bf16* __restrict__ wxlp, const float* __restrict__ bxl,
                 const float* __restrict__ winf, const float* __restrict__ cvecg,
                 const float* __restrict__ svecg,
                 float* __restrict__ shift_part, float* __restrict__ mi_part) {
    __shared__ __align__(16) __bf16 Ab[MM * SS];    // 33792 B (sred alias)
    __shared__ __align__(16) __bf16 Bb[MM * SS];    // 33792 B
    __shared__ __align__(16) __bf16 Lb[MM * LS];    // 5120 B (len2 stage)
    __shared__ __align__(16) float mired[4 * 256];  // 4 KB
    __shared__ __align__(16) float gatep[8 * 64];   // 2 KB
    __shared__ float gateb[MM];                     // 256 B   => 77.3 KB

    const int tid  = threadIdx.x;
    const int wave = tid >> 6;
    const int lane = tid & 63;
    const int col  = lane & 15;
    const int q    = lane >> 4;
    const int mt   = wave >> 1, nt = wave & 1;
    const int v    = nt * 16 + col;

    // ---- small tile-invariant prefetches ONLY (p1: 8 VGPR, bias: 1) ----
    WPre<2> p1 = prefW<2>(we1p, wave, lane);
    const float bias = bxl[v];

    // ---- prologue: stage first tile ----
    {
        int t0 = blockIdx.x;
        int c0 = t0 / NN, r0 = t0 - c0 * NN;
        stageLen2(Lb, nv, r0, c0 * MM, tid);
    }
    __syncthreads();                                                   // S0

    for (int t = blockIdx.x; t < NTILES; t += GRID) {
        const int chunk = t / NN;
        const int r     = t - chunk * NN;
        const int e0    = chunk * MM;
        const int tn    = t + GRID;
        const bool hasn = tn < NTILES;

        unsigned yv[16];

        // ---- h1 = silu(len2 @ We1' + svec + cvec): Lb -> Ab ----
        gemm1R(Lb, wave, lane, cvecg + r * UU, svecg, r, e0, yv, p1);
        writeY(Ab, wave, lane, yv);
        WPre<8> p2 = prefW<8>(we2p, wave, lane);
        __syncthreads();                                               // S2

        // ---- m = silu(h1 @ We2') + gate partials: Ab -> Bb ----
        gemm2G(Ab, we2p, wave, lane, winf, gatep, yv, p2);
        writeY(Bb, wave, lane, yv);
        if (hasn) {                       // stage NEXT tile (Lb free now)
            int cn = tn / NN, rn = tn - cn * NN;
            stageLen2(Lb, nv, rn, cn * MM, tid);
        }
        WPre<8> p3 = prefW<8>(wx1p, wave, lane);
        __syncthreads();                                               // S3

        // ---- redundant per-wave gate finalize (all 8 waves) ----
        {
            float s = 0.f;
#pragma unroll
            for (int w = 0; w < 8; ++w)
                s += gatep[w * 64 + lane];
            gateb[lane] = (e0 + lane == NN - 1) ? 0.f   // self-edge pad
                                                : fast_rcp(1.f + __expf(-s * 0.0625f));
        }
        // ---- mi partials: waves 0-3 read m (Bb); overlaps gemm3 ----
        if (tid < 256) {
            const int w   = tid >> 6;
            const int oct = lane & 31;
            const int egh = lane >> 5;
            const int eg  = w * 2 + egh;
            const __bf16* mp = Bb + (eg * 8) * SS + oct * 8;
            f32x4 g0 = *(const f32x4*)(gateb + eg * 8);
            f32x4 g1 = *(const f32x4*)(gateb + eg * 8 + 4);
            float p[8] = {0.f, 0.f, 0.f, 0.f, 0.f, 0.f, 0.f, 0.f};
#pragma unroll
            for (int i = 0; i < 8; ++i) {
                bf16v8 vv = *(const bf16v8*)(mp + i * SS);
                float gv = (i < 4) ? g0[i] : g1[i - 4];
#pragma unroll
                for (int j = 0; j < 8; ++j)
                    p[j] += (float)vv[j] * gv;
            }
#pragma unroll
            for (int j = 0; j < 8; ++j)            // combine eg pair (xor 32)
                p[j] += __shfl_xor(p[j], 32);
            if (egh == 0) {
                f32x4 a = {p[0], p[1], p[2], p[3]};
                f32x4 b = {p[4], p[5], p[6], p[7]};
                *(f32x4*)(mired + w * 256 + oct * 8)     = a;
                *(f32x4*)(mired + w * 256 + oct * 8 + 4) = b;
            }
        }
        // ---- t1 = silu(m @ Wx1'): Bb -> Ab ----
        gemmR<16, 8>(Bb, wx1p, wave, lane, yv, p3);
        writeY(Ab, wave, lane, yv);
        WPre<8> p4 = prefW<8>(wx2p, wave, lane);
        __syncthreads();                                               // S4

        // ---- mi finalize -> plain store; t2 = silu(t1 @ Wx2'): Ab -> Bb --
        if (tid < 256) {
            float s = mired[tid] + mired[256 + tid] + mired[512 + tid] + mired[768 + tid];
            mi_part[(chunk * NN + r) * UU + tid] = s;
        }
        gemmR<16, 8>(Ab, wx2p, wave, lane, yv, p4);
        writeY(Bb, wave, lane, yv);
        // phi_x weight pages: per-tile load (L2-hot), R25 placement
        bf16v8 pw[8];
#pragma unroll
        for (int kt = 0; kt < 8; ++kt)
            pw[kt] = *(const bf16v8*)(wxlp + kt * 1024 + v * 32 + q * 8);
        __syncthreads();                                               // S5

        // ---- phi_x MFMA + shift; reads Bb; sred -> Ab (dead) ----
        float sp0, sp1, sp2;
        {
            f32x4 acc = {bias, bias, bias, bias};
            const __bf16* xr = Bb + (mt * 16 + col) * SS + q * 8;
#pragma unroll
            for (int kt = 0; kt < 8; ++kt) {
                bf16v8 a = *(const bf16v8*)(xr + kt * 32);
                acc = __builtin_amdgcn_mfma_f32_16x16x32_bf16(a, pw[kt], acc, 0, 0, 0);
            }
            float r0 = nv[(r * 32 + v) * 3 + 0];
            float r1 = nv[(r * 32 + v) * 3 + 1];
            float r2 = nv[(r * 32 + v) * 3 + 2];
            sp0 = 0.f; sp1 = 0.f; sp2 = 0.f;
#pragma unroll
            for (int i = 0; i < 4; ++i) {
                int e = mt * 16 + q * 4 + i;
                int s = r + 1 + e0 + e; if (s >= NN) s -= NN;
                const float* ps = nv + (s * 32 + v) * 3;
                float d0 = r0 - ps[0], d1 = r1 - ps[1], d2 = r2 - ps[2];
                float len = fast_sqrt(fmaxf(d0 * d0 + d1 * d1 + d2 * d2, 1e-20f));
                float w = acc[i] * fast_rcp(1.f + len);   // self-edge -> 0
                sp0 += w * d0; sp1 += w * d1; sp2 += w * d2;
            }
        }
        float* sred = (float*)Ab;                  // [32 v][16 g][3 c] = 6KB
        {
            int g = mt * 4 + q;
            sred[v * 48 + g * 3 + 0] = sp0;
            sred[v * 48 + g * 3 + 1] = sp1;
            sred[v * 48 + g * 3 + 2] = sp2;
        }
        __syncthreads();                                               // S6

        // ---- reduce 16 groups -> plain store shift_part[chunk][r][96] ----
        if (tid < 96) {
            int vv = tid / 3, c = tid - vv * 3;
            float s = 0.f;
#pragma unroll
            for (int g = 0; g < 16; ++g)
                s += sred[vv * 48 + g * 3 + c];
            shift_part[(chunk * NN + r) * 96 + tid] = s;
        }
        __syncthreads();                                               // S1'
    }
}

// ---------------- node MLP (24 blocks x 16 rows, 16x16x32 MFMA) ------------
// B-operand from fmt32-packed weights via page remap:
//   k = q*8+j (q = lane>>4) -> page kt*2 + (q>>1), in-page (q&1)*8.
__global__ __launch_bounds__(512)
void node_kernel(const float* __restrict__ nv, const float* __restrict__ nf,
                 const __bf16* __restrict__ wh1p, const __bf16* __restrict__ wh2p,
                 const __bf16* __restrict__ whlp,
                 const float* __restrict__ shift_part, const float* __restrict__ mi_part,
                 float* __restrict__ out) {
    __shared__ __align__(16) __bf16 xsb[16 * XS];   // [m_i | nf] 16x384
    __shared__ __align__(16) __bf16 h1b[16 * SS];
    __shared__ __align__(16) __bf16 h2b[16 * SS];
    const int tid  = threadIdx.x;
    const int wave = tid >> 6;
    const int lane = tid & 63;
    const int cl   = lane & 15;
    const int q    = lane >> 4;
    const int n0   = blockIdx.x * 16;

    // ---- stage xs = [sum_k mi_part | nf]; vectors_out from shift_part ----
#pragma unroll
    for (int p = tid; p < 16 * 64; p += 512) {      // 2 iters, f32x4 quads
        int i = p >> 6, cq = (p & 63) * 4;
        f32x4 s = {0.f, 0.f, 0.f, 0.f};
#pragma unroll
        for (int k = 0; k < NCHUNK; ++k)
            s += *(const f32x4*)(mi_part + ((k * NN) + n0 + i) * UU + cq);
        bf16v4 bs = { (__bf16)s[0], (__bf16)s[1], (__bf16)s[2], (__bf16)s[3] };
        *(bf16v4*)&xsb[i * XS + cq] = bs;
    }
#pragma unroll
    for (int p = tid; p < 16 * 128; p += 512) {
        int i = p >> 7, c = p & 127;
        xsb[i * XS + 256 + c] = (__bf16)nf[(n0 + i) * HH + c];
    }
#pragma unroll
    for (int p = tid; p < 16 * 96; p += 512) {
        int i = p / 96, j = p - i * 96;
        float s = 0.f;
#pragma unroll
        for (int k = 0; k < NCHUNK; ++k)
            s += shift_part[((k * NN) + n0 + i) * 96 + j];
        out[(n0 + i) * 96 + j] = nv[(n0 + i) * 96 + j] + s * (1.f / 383.f);
    }
    __syncthreads();

    // ---- h1 = silu(xs @ Wh1'): 16 rows, wave covers 32 cols, K=384 ----
    {
        bf16v8 af[12];
        const __bf16* xr = xsb + cl * XS + q * 8;
#pragma unroll
        for (int kt = 0; kt < 12; ++kt)
            af[kt] = *(const bf16v8*)(xr + kt * 32);
#pragma unroll
        for (int nt = 0; nt < 2; ++nt) {
            int n = wave * 32 + nt * 16 + cl;
            f32x4 acc = {0.f, 0.f, 0.f, 0.f};
#pragma unroll
            for (int kt = 0; kt < 12; ++kt) {
                bf16v8 b = *(const bf16v8*)(wh1p + (kt * 2 + (q >> 1)) * 4096
                                            + n * 16 + (q & 1) * 8);
                acc = __builtin_amdgcn_mfma_f32_16x16x32_bf16(af[kt], b, acc, 0, 0, 0);
            }
#pragma unroll
            for (int i = 0; i < 4; ++i)
                h1b[(q * 4 + i) * SS + n] = (__bf16)fast_silu(acc[i]);
        }
    }
    __syncthreads();

    // ---- h2 = silu(h1 @ Wh2'): K=256 ----
    {
        bf16v8 af[8];
        const __bf16* xr = h1b + cl * SS + q * 8;
#pragma unroll
        for (int kt = 0; kt < 8; ++kt)
            af[kt] = *(const bf16v8*)(xr + kt * 32);
#pragma unroll
        for (int nt = 0; nt < 2; ++nt) {
            int n = wave * 32 + nt * 16 + cl;
            f32x4 acc = {0.f, 0.f, 0.f, 0.f};
#pragma unroll
            for (int kt = 0; kt < 8; ++kt) {
                bf16v8 b = *(const bf16v8*)(wh2p + (kt * 2 + (q >> 1)) * 4096
                                            + n * 16 + (q & 1) * 8);
                acc = __builtin_amdgcn_mfma_f32_16x16x32_bf16(af[kt], b, acc, 0, 0, 0);
            }
#pragma unroll
            for (int i = 0; i < 4; ++i)
                h2b[(q * 4 + i) * SS + n] = (__bf16)fast_silu(acc[i]);
        }
    }
    __syncthreads();

    // ---- features_out = h2 @ Whl' + nf  (N=128: 8 waves x 16 cols) ----
    {
        int n = wave * 16 + cl;
        f32x4 acc = {0.f, 0.f, 0.f, 0.f};
        const __bf16* xr = h2b + cl * SS + q * 8;
#pragma unroll
        for (int kt = 0; kt < 8; ++kt) {
            bf16v8 a = *(const bf16v8*)(xr + kt * 32);
            bf16v8 b = *(const bf16v8*)(whlp + kt * 4096 + n * 32 + q * 8);
            acc = __builtin_amdgcn_mfma_f32_16x16x32_bf16(a, b, acc, 0, 0, 0);
        }
#pragma unroll
        for (int i = 0; i < 4; ++i) {
            int row = n0 + q * 4 + i;
            out[NN * 96 + row * HH + n] = acc[i] + nf[row * HH + n];
        }
    }
}

// ------------------------------- launcher ----------------------------------
extern "C" void kernel_launch(void* const* d_in, const int* in_sizes, int n_in,
                              void* d_out, int out_size, void* d_ws, size_t ws_size,
                              hipStream_t stream) {
    const float* nv   = (const float*)d_in[0];
    const float* nf   = (const float*)d_in[1];
    const float* We1  = (const float*)d_in[2];
    const float* We2  = (const float*)d_in[3];
    const float* Wx1  = (const float*)d_in[4];
    const float* Wx2  = (const float*)d_in[5];
    const float* Wxl  = (const float*)d_in[6];
    const float* bxl  = (const float*)d_in[7];
    const float* Winf = (const float*)d_in[8];
    const float* Wh1  = (const float*)d_in[9];
    const float* Wh2  = (const float*)d_in[10];
    const float* Whl  = (const float*)d_in[11];
    float* out = (float*)d_out;

    char* ws = (char*)d_ws;
    float*  mi_part    = (float*)ws;                    // 6*384*256*4 = 2359296
    float*  shift_part = (float*)(ws + 2359296);        // 6*384*96*4  = 884736
    float*  cvecg  = (float*)(ws + 3244032);            // 393216
    float*  svecg  = (float*)(ws + 3637248);            // 393216
    __bf16* we1p   = (__bf16*)(ws + 4030464);           // 16384 (k rows 0..31)
    __bf16* we2p   = (__bf16*)(ws + 4046848);           // 131072
    __bf16* wx1p   = (__bf16*)(ws + 4177920);           // 131072
    __bf16* wx2p   = (__bf16*)(ws + 4308992);           // 131072
    __bf16* wh1p   = (__bf16*)(ws + 4440064);           // 196608
    __bf16* wh2p   = (__bf16*)(ws + 4636672);           // 131072
    __bf16* wxlp   = (__bf16*)(ws + 4767744);           // 16384
    __bf16* whlp   = (__bf16*)(ws + 4784128);           // 65536

    repack_all<<<dim3(724), 256, 0, stream>>>(We1, We2, Wx1, Wx2, Wh1, Wh2, Wxl, Whl,
                                              nf, we1p, we2p, wx1p, wx2p,
                                              wh1p, wh2p, wxlp, whlp, cvecg, svecg);

    edge_kernel<<<dim3(GRID), 512, 0, stream>>>(nv, nf, we1p, we2p, wx1p, wx2p,
                                                wxlp, bxl, Winf, cvecg, svecg,
                                                shift_part, mi_part);
    node_kernel<<<dim3(24), 512, 0, stream>>>(nv, nf, wh1p, wh2p, whlp,
                                              shift_part, mi_part, out);
}

// Round 12
// 195.120 us; speedup vs baseline: 2.1211x; 2.0828x over previous
//
#include <hip/hip_runtime.h>
#include <hip/hip_bf16.h>

// EGCL (EGNN layer): N=384 nodes, V=32 vectors, H=128 feats, U=256 width.
// E = N*(N-1) = 147072 fully-connected edges. f32 in/out, bf16 MFMA compute.
// Edges grouped by RECEIVER r: segment sums are in-block reductions.
// R28 = R25 RESTORED (verified best: edge 111.2us, total 197.7us).
// R26/R27 persistent-block attempts both hit intrinsic loop-carried spill
// traffic (FETCH 506MB) regardless of hoist placement -> direction dead.
// The proven ladder: R22 phase-structure (ping-pong 6-barrier + cross-
// barrier weight prefetch, +10%) -> R25 prefetch depth 8 + 8-wave mi
// balance (+2.5%). Everything else (occupancy 40->78%, L2 volume 2x,
// LDS-instr cuts, atomics->0, operand swaps, setprio, node 2x blocks,
// persistence) was null or negative across 11 measured rounds.

#define NN 384
#define VV 32
#define HH 128
#define UU 256
#define MM 64            // edges per block
#define NCHUNK 6         // 6*64 = 384 = 383 edges + 1 pad
#define SS 264           // LDS row stride edge buffer (256-wide, +8 pad)
#define XS 392           // node xs row stride (384-wide, +8 pad)

typedef __bf16 bf16v8 __attribute__((ext_vector_type(8)));
typedef __bf16 bf16v4 __attribute__((ext_vector_type(4)));
typedef float  f32x4  __attribute__((ext_vector_type(4)));
typedef float  f32x16 __attribute__((ext_vector_type(16)));
typedef unsigned u32x2 __attribute__((ext_vector_type(2)));

__device__ __forceinline__ float fast_rcp(float x) { return __builtin_amdgcn_rcpf(x); }
__device__ __forceinline__ float fast_sqrt(float x) { return __builtin_amdgcn_sqrtf(x); }
__device__ __forceinline__ float fast_silu(float v) {
    return v * __builtin_amdgcn_rcpf(1.f + __expf(-v));
}
__device__ __forceinline__ unsigned pack_silu2(float a, float b) {
    unsigned short l = __builtin_bit_cast(unsigned short, (__bf16)fast_silu(a));
    unsigned short h = __builtin_bit_cast(unsigned short, (__bf16)fast_silu(b));
    return (unsigned)l | ((unsigned)h << 16);
}
__device__ __forceinline__ unsigned pack_bf2(float a, float b) {
    unsigned short l = __builtin_bit_cast(unsigned short, (__bf16)a);
    unsigned short h = __builtin_bit_cast(unsigned short, (__bf16)b);
    return (unsigned)l | ((unsigned)h << 16);
}

// ---------------- repack + cvec/svec ---------------------------------------
// blocks [0,180): fmt32 transpose tiles; [180,340): scalar fmt16;
// [340,724): cvecg+svecg merged (one nf row read, 2 accumulators).
__global__ __launch_bounds__(256)
void repack_all(const float* __restrict__ We1, const float* __restrict__ We2,
                const float* __restrict__ Wx1, const float* __restrict__ Wx2,
                const float* __restrict__ Wh1, const float* __restrict__ Wh2,
                const float* __restrict__ Wxl, const float* __restrict__ Whl,
                const float* __restrict__ nf,
                __bf16* __restrict__ we1p, __bf16* __restrict__ we2p,
                __bf16* __restrict__ wx1p, __bf16* __restrict__ wx2p,
                __bf16* __restrict__ wh1p, __bf16* __restrict__ wh2p,
                __bf16* __restrict__ wxlp, __bf16* __restrict__ whlp,
                float* __restrict__ cvecg, float* __restrict__ svecg) {
    const float s288 = 0.05892556509887896f;   // 1/sqrt(288)
    const float s384 = 0.05103103630798288f;   // 1/sqrt(384)
    const float s16  = 0.0625f;
    const int b   = blockIdx.x;
    const int tid = threadIdx.x;

    if (b < 180) {                               // ---- fmt32 transpose tiles
        __shared__ __bf16 T[32 * 72];
        const float* src; __bf16* dst; int tile; float scale;
        if (b < 4)        { src = We1; dst = we1p; tile = b;       scale = s288; }
        else if (b < 36)  { src = We2; dst = we2p; tile = b - 4;   scale = s16;  }
        else if (b < 68)  { src = Wx1; dst = wx1p; tile = b - 36;  scale = s16;  }
        else if (b < 100) { src = Wx2; dst = wx2p; tile = b - 68;  scale = s16;  }
        else if (b < 148) { src = Wh1; dst = wh1p; tile = b - 100; scale = s384; }
        else              { src = Wh2; dst = wh2p; tile = b - 148; scale = s16;  }
        const int kt0 = tile >> 2, nt0 = tile & 3;
        const int k0 = kt0 * 32, n0 = nt0 * 64;
#pragma unroll
        for (int i = 0; i < 8; ++i) {
            int p = tid + i * 256;
            int k = p >> 6, n = p & 63;
            T[k * 72 + n] = (__bf16)(src[(k0 + k) * 256 + n0 + n] * scale);
        }
        __syncthreads();
        const int ktl = tid >> 7, rem = tid & 127;
        const int n = rem >> 1, kh = rem & 1;
        bf16v8 v;
#pragma unroll
        for (int j = 0; j < 8; ++j)
            v[j] = T[(ktl * 16 + kh * 8 + j) * 72 + n];
        *(bf16v8*)(dst + (kt0 * 2 + ktl) * 4096 + (n0 + n) * 16 + kh * 8) = v;
        return;
    }
    if (b < 340) {      // ---- scalar fmt16: Wxl (8192 el), Whl (32768 el)
        int t = (b - 180) * 256 + tid;
        const float* src; __bf16* dst; int Nout; int idx; float scale;
        if (t < 8192)       { src = Wxl; dst = wxlp; Nout = 32;  idx = t;        scale = 1.0f; }
        else if (t < 40960) { src = Whl; dst = whlp; Nout = 128; idx = t - 8192; scale = s16;  }
        else return;
        int kt  = idx / (Nout * 32);
        int rem = idx - kt * Nout * 32;
        int n   = rem >> 5;
        int kk  = rem & 31;
        dst[idx] = (__bf16)(src[(kt * 32 + kk) * Nout + n] * scale);
        return;
    }
    // ---- merged cvec/svec: node i, two accumulators, nf read once ----
    {
        int i = b - 340;
        float a = 0.f, c = 0.f;
#pragma unroll 4
        for (int k = 0; k < 128; ++k) {
            float nfv = nf[i * HH + k];
            a += nfv * We1[(32 + k) * 256 + tid];
            c += nfv * We1[(160 + k) * 256 + tid];
        }
        svecg[i * UU + tid] = a * s288;
        cvecg[i * UU + tid] = c * s288;
    }
}

// ---- weight prefetch: first NP kt-pages of a gemm's B rows ----------------
template <int NP> struct WPre { bf16v8 w[NP]; };
template <int NP>
__device__ __forceinline__ WPre<NP> prefW(const __bf16* __restrict__ P,
                                          int wave, int lane) {
    const int idx = lane & 31;
    const int kh  = lane >> 5;
    const __bf16* wr = P + (wave * 32 + idx) * 16 + kh * 8;
    WPre<NP> r;
#pragma unroll
    for (int i = 0; i < NP; ++i)
        r.w[i] = *(const bf16v8*)(wr + i * 4096);
    return r;
}

// ---- swapped 64x256 GEMM: yv = packed silu((X @ Wp)^T), in regs -----------
// D: lane holds edge = lane&31 (acc0) / +32 (acc1); cols 8g+4kh+t in-wave.
template <int KT, int NP>
__device__ __forceinline__ void gemmR(const __bf16* X,
                                      const __bf16* __restrict__ P,
                                      int wave, int lane, unsigned* yv,
                                      const WPre<NP>& pre) {
    const int idx = lane & 31;
    const int kh  = lane >> 5;
    f32x16 acc0 = {}, acc1 = {};
    const __bf16* xb = X + idx * SS + kh * 8;
    const __bf16* wr = P + (wave * 32 + idx) * 16 + kh * 8;
#pragma unroll
    for (int kt = 0; kt < KT; ++kt) {
        bf16v8 w  = (kt < NP) ? pre.w[kt < NP ? kt : 0]
                              : *(const bf16v8*)(wr + kt * 4096);
        bf16v8 x0 = *(const bf16v8*)(xb + kt * 16);
        bf16v8 x1 = *(const bf16v8*)(xb + 32 * SS + kt * 16);
        acc0 = __builtin_amdgcn_mfma_f32_32x32x16_bf16(w, x0, acc0, 0, 0, 0);
        acc1 = __builtin_amdgcn_mfma_f32_32x32x16_bf16(w, x1, acc1, 0, 0, 0);
    }
#pragma unroll
    for (int g = 0; g < 4; ++g) {
        yv[2 * g]       = pack_silu2(acc0[4 * g + 0], acc0[4 * g + 1]);
        yv[2 * g + 1]   = pack_silu2(acc0[4 * g + 2], acc0[4 * g + 3]);
        yv[8 + 2 * g]   = pack_silu2(acc1[4 * g + 0], acc1[4 * g + 1]);
        yv[9 + 2 * g]   = pack_silu2(acc1[4 * g + 2], acc1[4 * g + 3]);
    }
}

// writeback: lane's edge row, 4 quads x b64 per acc tile
__device__ __forceinline__ void writeY(__bf16* Y, int wave, int lane,
                                       const unsigned* yv) {
    const int e  = lane & 31;
    const int kh = lane >> 5;
    __bf16* p0 = Y + e * SS + wave * 32 + 4 * kh;
#pragma unroll
    for (int g = 0; g < 4; ++g) {
        u32x2 a = { yv[2 * g], yv[2 * g + 1] };
        u32x2 b = { yv[8 + 2 * g], yv[9 + 2 * g] };
        *(u32x2*)(p0 + g * 8) = a;
        *(u32x2*)(p0 + 32 * SS + g * 8) = b;
    }
}

// ---- gemm1 swapped: yv = silu(len2 @ We1'[0:32] + svec[s] + cvec[r]) ------
__device__ __forceinline__ void gemm1R(const __bf16* X,
                                       int wave, int lane,
                                       const float* __restrict__ cvec,
                                       const float* __restrict__ svecg,
                                       int r, int e0, unsigned* yv,
                                       const WPre<2>& pre) {
    const int idx = lane & 31;
    const int kh  = lane >> 5;
    f32x16 acc0 = {}, acc1 = {};
    const __bf16* xb = X + idx * SS + kh * 8;
    bf16v8 x00 = *(const bf16v8*)(xb);
    bf16v8 x01 = *(const bf16v8*)(xb + 16);
    bf16v8 x10 = *(const bf16v8*)(xb + 32 * SS);
    bf16v8 x11 = *(const bf16v8*)(xb + 32 * SS + 16);
    acc0 = __builtin_amdgcn_mfma_f32_32x32x16_bf16(pre.w[0], x00, acc0, 0, 0, 0);
    acc0 = __builtin_amdgcn_mfma_f32_32x32x16_bf16(pre.w[1], x01, acc0, 0, 0, 0);
    acc1 = __builtin_amdgcn_mfma_f32_32x32x16_bf16(pre.w[0], x10, acc1, 0, 0, 0);
    acc1 = __builtin_amdgcn_mfma_f32_32x32x16_bf16(pre.w[1], x11, acc1, 0, 0, 0);
    int s0 = r + 1 + e0 + idx; if (s0 >= NN) s0 -= NN;
    int s1 = s0 + 32;          if (s1 >= NN) s1 -= NN;
    const int nb = wave * 32 + 4 * kh;
    const float* cp  = cvec + nb;
    const float* sp0 = svecg + s0 * UU + nb;
    const float* sp1 = svecg + s1 * UU + nb;
#pragma unroll
    for (int g = 0; g < 4; ++g) {
        f32x4 c = *(const f32x4*)(cp + 8 * g);
        f32x4 a = *(const f32x4*)(sp0 + 8 * g);
        f32x4 b = *(const f32x4*)(sp1 + 8 * g);
        yv[2 * g]     = pack_silu2(acc0[4 * g + 0] + c[0] + a[0],
                                   acc0[4 * g + 1] + c[1] + a[1]);
        yv[2 * g + 1] = pack_silu2(acc0[4 * g + 2] + c[2] + a[2],
                                   acc0[4 * g + 3] + c[3] + a[3]);
        yv[8 + 2 * g] = pack_silu2(acc1[4 * g + 0] + c[0] + b[0],
                                   acc1[4 * g + 1] + c[1] + b[1]);
        yv[9 + 2 * g] = pack_silu2(acc1[4 * g + 2] + c[2] + b[2],
                                   acc1[4 * g + 3] + c[3] + b[3]);
    }
}

// ---- gemm2 + fused gate partials (silu applied here, packed plain) --------
template <int NP>
__device__ __forceinline__ void gemm2G(const __bf16* X,
                                       const __bf16* __restrict__ P,
                                       int wave, int lane,
                                       const float* __restrict__ winf,
                                       float* __restrict__ gatep, unsigned* yv,
                                       const WPre<NP>& pre) {
    const int idx = lane & 31;
    const int kh  = lane >> 5;
    f32x16 acc0 = {}, acc1 = {};
    const __bf16* xb = X + idx * SS + kh * 8;
    const __bf16* wr = P + (wave * 32 + idx) * 16 + kh * 8;
#pragma unroll
    for (int kt = 0; kt < 16; ++kt) {
        bf16v8 w  = (kt < NP) ? pre.w[kt < NP ? kt : 0]
                              : *(const bf16v8*)(wr + kt * 4096);
        bf16v8 x0 = *(const bf16v8*)(xb + kt * 16);
        bf16v8 x1 = *(const bf16v8*)(xb + 32 * SS + kt * 16);
        acc0 = __builtin_amdgcn_mfma_f32_32x32x16_bf16(w, x0, acc0, 0, 0, 0);
        acc1 = __builtin_amdgcn_mfma_f32_32x32x16_bf16(w, x1, acc1, 0, 0, 0);
    }
    const int nb = wave * 32 + 4 * kh;
    float gp0 = 0.f, gp1 = 0.f;
#pragma unroll
    for (int g = 0; g < 4; ++g) {
        f32x4 wv = *(const f32x4*)(winf + nb + 8 * g);
        float u0 = fast_silu(acc0[4 * g + 0]), u1 = fast_silu(acc0[4 * g + 1]);
        float u2 = fast_silu(acc0[4 * g + 2]), u3 = fast_silu(acc0[4 * g + 3]);
        float v0 = fast_silu(acc1[4 * g + 0]), v1 = fast_silu(acc1[4 * g + 1]);
        float v2 = fast_silu(acc1[4 * g + 2]), v3 = fast_silu(acc1[4 * g + 3]);
        gp0 += u0 * wv[0] + u1 * wv[1] + u2 * wv[2] + u3 * wv[3];
        gp1 += v0 * wv[0] + v1 * wv[1] + v2 * wv[2] + v3 * wv[3];
        yv[2 * g]     = pack_bf2(u0, u1);
        yv[2 * g + 1] = pack_bf2(u2, u3);
        yv[8 + 2 * g] = pack_bf2(v0, v1);
        yv[9 + 2 * g] = pack_bf2(v2, v3);
    }
    gp0 += __shfl_xor(gp0, 32);                 // combine kh col-halves
    gp1 += __shfl_xor(gp1, 32);
    if (kh == 0) {
        gatep[wave * 64 + idx]      = gp0;
        gatep[wave * 64 + 32 + idx] = gp1;
    }
}

// --------------------------- fused edge kernel -----------------------------
__global__ __launch_bounds__(512, 4)
void edge_kernel(const float* __restrict__ nv, const float* __restrict__ nf,
                 const __bf16* __restrict__ we1p, const __bf16* __restrict__ we2p,
                 const __bf16* __restrict__ wx1p, const __bf16* __restrict__ wx2p,
                 const __bf16* __restrict__ wxlp, const float* __restrict__ bxl,
                 const float* __restrict__ winf, const float* __restrict__ cvecg,
                 const float* __restrict__ svecg,
                 float* __restrict__ shift_part, float* __restrict__ mi_part) {
    __shared__ __align__(16) __bf16 Ab[MM * SS];    // 33792 B
    __shared__ __align__(16) __bf16 Bb[MM * SS];    // 33792 B (sred alias)
    __shared__ __align__(16) float mired[8 * 256];  // 8 KB
    __shared__ __align__(16) float gatep[8 * 64];   // 2 KB
    __shared__ float gateb[MM];                     // 256 B

    const int tid  = threadIdx.x;
    const int wave = tid >> 6;
    const int lane = tid & 63;
    const int col  = lane & 15;
    const int q    = lane >> 4;
    const int r     = blockIdx.y;
    const int chunk = blockIdx.x;
    const int e0    = chunk * MM;

    unsigned yv[16];

    // prefetch gemm1 weights immediately (in flight during staging)
    WPre<2> p1 = prefW<2>(we1p, wave, lane);

    // ---- stage: len2 (cols 0..31; nf terms hoisted into svecg/cvecg) ----
#pragma unroll
    for (int p = tid; p < MM * 16; p += 512) {     // 2 iters, packed b32
        int i = p >> 4, v = (p & 15) << 1;
        int s = r + 1 + e0 + i; if (s >= NN) s -= NN;
        const float* pr = nv + (r * 32 + v) * 3;
        const float* ps = nv + (s * 32 + v) * 3;
        float a0 = pr[0] - ps[0], a1 = pr[1] - ps[1], a2 = pr[2] - ps[2];
        float b0 = pr[3] - ps[3], b1 = pr[4] - ps[4], b2 = pr[5] - ps[5];
        *(unsigned*)&Ab[i * SS + v] = pack_bf2(a0 * a0 + a1 * a1 + a2 * a2,
                                               b0 * b0 + b1 * b1 + b2 * b2);
    }
    __syncthreads();                                                   // S1

    // ---- h1 = silu(len2 @ We1' + svec + cvec): Ab -> Bb ----
    gemm1R(Ab, wave, lane, cvecg + r * UU, svecg, r, e0, yv, p1);
    writeY(Bb, wave, lane, yv);
    WPre<8> p2 = prefW<8>(we2p, wave, lane);       // flies across S2
    __syncthreads();                                                   // S2

    // ---- m = silu(h1 @ We2') + gate partials: Bb -> Ab ----
    gemm2G(Bb, we2p, wave, lane, winf, gatep, yv, p2);
    writeY(Ab, wave, lane, yv);
    WPre<8> p3 = prefW<8>(wx1p, wave, lane);
    __syncthreads();                                                   // S3

    // ---- redundant per-wave gate finalize (all 8 waves, same values) ----
    {
        float s = 0.f;
#pragma unroll
        for (int w = 0; w < 8; ++w)
            s += gatep[w * 64 + lane];
        gateb[lane] = (e0 + lane == NN - 1) ? 0.f  // self-edge pad
                                            : fast_rcp(1.f + __expf(-s * 0.0625f));
    }
    // ---- mi partials: ALL 8 waves, wave owns 8 edges; overlaps gemm3 ----
    {
        const int oct = lane & 31;
        const int egh = lane >> 5;                 // edges 0-3 vs 4-7
        const __bf16* mp = Ab + (wave * 8 + egh * 4) * SS + oct * 8;
        f32x4 g = *(const f32x4*)(gateb + wave * 8 + egh * 4);
        float p[8] = {0.f, 0.f, 0.f, 0.f, 0.f, 0.f, 0.f, 0.f};
#pragma unroll
        for (int i = 0; i < 4; ++i) {
            bf16v8 v = *(const bf16v8*)(mp + i * SS);
            float gv = g[i];
#pragma unroll
            for (int j = 0; j < 8; ++j)
                p[j] += (float)v[j] * gv;
        }
#pragma unroll
        for (int j = 0; j < 8; ++j)                // combine egh halves
            p[j] += __shfl_xor(p[j], 32);
        if (egh == 0) {
            f32x4 a = {p[0], p[1], p[2], p[3]};
            f32x4 b = {p[4], p[5], p[6], p[7]};
            *(f32x4*)(mired + wave * 256 + oct * 8)     = a;
            *(f32x4*)(mired + wave * 256 + oct * 8 + 4) = b;
        }
    }
    // ---- t1 = silu(m @ Wx1'): Ab -> Bb ----
    gemmR<16, 8>(Ab, wx1p, wave, lane, yv, p3);
    writeY(Bb, wave, lane, yv);
    WPre<8> p4 = prefW<8>(wx2p, wave, lane);
    __syncthreads();                                                   // S4

    // ---- mi finalize -> plain store; t2 = silu(t1 @ Wx2'): Bb -> Ab ----
    if (tid < 256) {
        float s = 0.f;
#pragma unroll
        for (int w = 0; w < 8; ++w)
            s += mired[w * 256 + tid];
        mi_part[(chunk * NN + r) * UU + tid] = s;
    }
    gemmR<16, 8>(Bb, wx2p, wave, lane, yv, p4);
    writeY(Ab, wave, lane, yv);
    // prefetch ALL phi_x weight pages (16KB total; 8x16B per lane)
    int mt = wave >> 1, nt = wave & 1;
    int v = nt * 16 + col;
    bf16v8 pw[8];
#pragma unroll
    for (int kt = 0; kt < 8; ++kt)
        pw[kt] = *(const bf16v8*)(wxlp + kt * 1024 + v * 32 + q * 8);
    __syncthreads();                                                   // S5

    // ---- phi_x MFMA + shift; sred -> Bb (dead after S5) ----
    float sp0, sp1, sp2;
    {
        float bias = bxl[v];
        f32x4 acc = {bias, bias, bias, bias};
        const __bf16* xr = Ab + (mt * 16 + col) * SS + q * 8;
#pragma unroll
        for (int kt = 0; kt < 8; ++kt) {
            bf16v8 a = *(const bf16v8*)(xr + kt * 32);
            acc = __builtin_amdgcn_mfma_f32_16x16x32_bf16(a, pw[kt], acc, 0, 0, 0);
        }
        float r0 = nv[(r * 32 + v) * 3 + 0];
        float r1 = nv[(r * 32 + v) * 3 + 1];
        float r2 = nv[(r * 32 + v) * 3 + 2];
        sp0 = 0.f; sp1 = 0.f; sp2 = 0.f;
#pragma unroll
        for (int i = 0; i < 4; ++i) {
            int e = mt * 16 + q * 4 + i;
            int s = r + 1 + e0 + e; if (s >= NN) s -= NN;
            const float* ps = nv + (s * 32 + v) * 3;
            float d0 = r0 - ps[0], d1 = r1 - ps[1], d2 = r2 - ps[2];
            float len = fast_sqrt(fmaxf(d0 * d0 + d1 * d1 + d2 * d2, 1e-20f));
            float w = acc[i] * fast_rcp(1.f + len);   // self-edge: d=0 -> 0
            sp0 += w * d0; sp1 += w * d1; sp2 += w * d2;
        }
    }
    float* sred = (float*)Bb;                      // [32 v][16 g][3 c] = 6KB
    {
        int g = mt * 4 + q;
        sred[v * 48 + g * 3 + 0] = sp0;
        sred[v * 48 + g * 3 + 1] = sp1;
        sred[v * 48 + g * 3 + 2] = sp2;
    }
    __syncthreads();                                                   // S6

    // ---- reduce 16 groups -> plain store shift_part[chunk][r][96] ----
    if (tid < 96) {
        int vv = tid / 3, c = tid - vv * 3;
        float s = 0.f;
#pragma unroll
        for (int g = 0; g < 16; ++g)
            s += sred[vv * 48 + g * 3 + c];
        shift_part[(chunk * NN + r) * 96 + tid] = s;
    }
}

// ---------------- node MLP (24 blocks x 16 rows, 16x16x32 MFMA) ------------
// B-operand from fmt32-packed weights via page remap:
//   k = q*8+j (q = lane>>4) -> page kt*2 + (q>>1), in-page (q&1)*8.
__global__ __launch_bounds__(512)
void node_kernel(const float* __restrict__ nv, const float* __restrict__ nf,
                 const __bf16* __restrict__ wh1p, const __bf16* __restrict__ wh2p,
                 const __bf16* __restrict__ whlp,
                 const float* __restrict__ shift_part, const float* __restrict__ mi_part,
                 float* __restrict__ out) {
    __shared__ __align__(16) __bf16 xsb[16 * XS];   // [m_i | nf] 16x384
    __shared__ __align__(16) __bf16 h1b[16 * SS];
    __shared__ __align__(16) __bf16 h2b[16 * SS];
    const int tid  = threadIdx.x;
    const int wave = tid >> 6;
    const int lane = tid & 63;
    const int cl   = lane & 15;
    const int q    = lane >> 4;
    const int n0   = blockIdx.x * 16;

    // ---- stage xs = [sum_k mi_part | nf]; vectors_out from shift_part ----
#pragma unroll
    for (int p = tid; p < 16 * 64; p += 512) {      // 2 iters, f32x4 quads
        int i = p >> 6, cq = (p & 63) * 4;
        f32x4 s = {0.f, 0.f, 0.f, 0.f};
#pragma unroll
        for (int k = 0; k < NCHUNK; ++k)
            s += *(const f32x4*)(mi_part + ((k * NN) + n0 + i) * UU + cq);
        bf16v4 bs = { (__bf16)s[0], (__bf16)s[1], (__bf16)s[2], (__bf16)s[3] };
        *(bf16v4*)&xsb[i * XS + cq] = bs;
    }
#pragma unroll
    for (int p = tid; p < 16 * 128; p += 512) {
        int i = p >> 7, c = p & 127;
        xsb[i * XS + 256 + c] = (__bf16)nf[(n0 + i) * HH + c];
    }
#pragma unroll
    for (int p = tid; p < 16 * 96; p += 512) {
        int i = p / 96, j = p - i * 96;
        float s = 0.f;
#pragma unroll
        for (int k = 0; k < NCHUNK; ++k)
            s += shift_part[((k * NN) + n0 + i) * 96 + j];
        out[(n0 + i) * 96 + j] = nv[(n0 + i) * 96 + j] + s * (1.f / 383.f);
    }
    __syncthreads();

    // ---- h1 = silu(xs @ Wh1'): 16 rows, wave covers 32 cols, K=384 ----
    {
        bf16v8 af[12];
        const __bf16* xr = xsb + cl * XS + q * 8;
#pragma unroll
        for (int kt = 0; kt < 12; ++kt)
            af[kt] = *(const bf16v8*)(xr + kt * 32);
#pragma unroll
        for (int nt = 0; nt < 2; ++nt) {
            int n = wave * 32 + nt * 16 + cl;
            f32x4 acc = {0.f, 0.f, 0.f, 0.f};
#pragma unroll
            for (int kt = 0; kt < 12; ++kt) {
                bf16v8 b = *(const bf16v8*)(wh1p + (kt * 2 + (q >> 1)) * 4096
                                            + n * 16 + (q & 1) * 8);
                acc = __builtin_amdgcn_mfma_f32_16x16x32_bf16(af[kt], b, acc, 0, 0, 0);
            }
#pragma unroll
            for (int i = 0; i < 4; ++i)
                h1b[(q * 4 + i) * SS + n] = (__bf16)fast_silu(acc[i]);
        }
    }
    __syncthreads();

    // ---- h2 = silu(h1 @ Wh2'): K=256 ----
    {
        bf16v8 af[8];
        const __bf16* xr = h1b + cl * SS + q * 8;
#pragma unroll
        for (int kt = 0; kt < 8; ++kt)
            af[kt] = *(const bf16v8*)(xr + kt * 32);
#pragma unroll
        for (int nt = 0; nt < 2; ++nt) {
            int n = wave * 32 + nt * 16 + cl;
            f32x4 acc = {0.f, 0.f, 0.f, 0.f};
#pragma unroll
            for (int kt = 0; kt < 8; ++kt) {
                bf16v8 b = *(const bf16v8*)(wh2p + (kt * 2 + (q >> 1)) * 4096
                                            + n * 16 + (q & 1) * 8);
                acc = __builtin_amdgcn_mfma_f32_16x16x32_bf16(af[kt], b, acc, 0, 0, 0);
            }
#pragma unroll
            for (int i = 0; i < 4; ++i)
                h2b[(q * 4 + i) * SS + n] = (__bf16)fast_silu(acc[i]);
        }
    }
    __syncthreads();

    // ---- features_out = h2 @ Whl' + nf  (N=128: 8 waves x 16 cols) ----
    {
        int n = wave * 16 + cl;
        f32x4 acc = {0.f, 0.f, 0.f, 0.f};
        const __bf16* xr = h2b + cl * SS + q * 8;
#pragma unroll
        for (int kt = 0; kt < 8; ++kt) {
            bf16v8 a = *(const bf16v8*)(xr + kt * 32);
            bf16v8 b = *(const bf16v8*)(whlp + kt * 4096 + n * 32 + q * 8);
            acc = __builtin_amdgcn_mfma_f32_16x16x32_bf16(a, b, acc, 0, 0, 0);
        }
#pragma unroll
        for (int i = 0; i < 4; ++i) {
            int row = n0 + q * 4 + i;
            out[NN * 96 + row * HH + n] = acc[i] + nf[row * HH + n];
        }
    }
}

// ------------------------------- launcher ----------------------------------
extern "C" void kernel_launch(void* const* d_in, const int* in_sizes, int n_in,
                              void* d_out, int out_size, void* d_ws, size_t ws_size,
                              hipStream_t stream) {
    const float* nv   = (const float*)d_in[0];
    const float* nf   = (const float*)d_in[1];
    const float* We1  = (const float*)d_in[2];
    const float* We2  = (const float*)d_in[3];
    const float* Wx1  = (const float*)d_in[4];
    const float* Wx2  = (const float*)d_in[5];
    const float* Wxl  = (const float*)d_in[6];
    const float* bxl  = (const float*)d_in[7];
    const float* Winf = (const float*)d_in[8];
    const float* Wh1  = (const float*)d_in[9];
    const float* Wh2  = (const float*)d_in[10];
    const float* Whl  = (const float*)d_in[11];
    float* out = (float*)d_out;

    char* ws = (char*)d_ws;
    float*  mi_part    = (float*)ws;                    // 6*384*256*4 = 2359296
    float*  shift_part = (float*)(ws + 2359296);        // 6*384*96*4  = 884736
    float*  cvecg  = (float*)(ws + 3244032);            // 393216
    float*  svecg  = (float*)(ws + 3637248);            // 393216
    __bf16* we1p   = (__bf16*)(ws + 4030464);           // 16384 (k rows 0..31)
    __bf16* we2p   = (__bf16*)(ws + 4046848);           // 131072
    __bf16* wx1p   = (__bf16*)(ws + 4177920);           // 131072
    __bf16* wx2p   = (__bf16*)(ws + 4308992);           // 131072
    __bf16* wh1p   = (__bf16*)(ws + 4440064);           // 196608
    __bf16* wh2p   = (__bf16*)(ws + 4636672);           // 131072
    __bf16* wxlp   = (__bf16*)(ws + 4767744);           // 16384
    __bf16* whlp   = (__bf16*)(ws + 4784128);           // 65536

    repack_all<<<dim3(724), 256, 0, stream>>>(We1, We2, Wx1, Wx2, Wh1, Wh2, Wxl, Whl,
                                              nf, we1p, we2p, wx1p, wx2p,
                                              wh1p, wh2p, wxlp, whlp, cvecg, svecg);

    edge_kernel<<<dim3(NCHUNK, NN), 512, 0, stream>>>(nv, nf, we1p, we2p, wx1p, wx2p,
                                                      wxlp, bxl, Winf, cvecg, svecg,
                                                      shift_part, mi_part);
    node_kernel<<<dim3(24), 512, 0, stream>>>(nv, nf, wh1p, wh2p, whlp,
                                              shift_part, mi_part, out);
}